// Round 1
// baseline (2565.284 us; speedup 1.0000x reference)
//
#include <hip/hip_runtime.h>
#include <hip/hip_bf16.h>

#define NUSER 200000
#define NEVENT 50000
#define NEDGE 2000000
#define FIN 256
#define HD 128
#define NLAYER 2

// ---------------------------------------------------------------- CSR build
__global__ void count_edges(const int* __restrict__ dst, int* __restrict__ cnt, int n) {
  int stride = gridDim.x * blockDim.x;
  for (int i = blockIdx.x * blockDim.x + threadIdx.x; i < n; i += stride)
    atomicAdd(&cnt[dst[i]], 1);
}

__global__ void scan_blocks(const int* __restrict__ cnt, int* __restrict__ excl,
                            int* __restrict__ partials, int n) {
  __shared__ int sh[256];
  int t = threadIdx.x;
  int i = blockIdx.x * 256 + t;
  int v = (i < n) ? cnt[i] : 0;
  sh[t] = v;
  __syncthreads();
  for (int off = 1; off < 256; off <<= 1) {
    int y = (t >= off) ? sh[t - off] : 0;
    __syncthreads();
    sh[t] += y;
    __syncthreads();
  }
  if (i < n) excl[i] = sh[t] - v;
  if (t == 255) partials[blockIdx.x] = sh[255];
}

__global__ void scan_partials(int* __restrict__ partials, int nb) {
  __shared__ int sh[1024];
  int t = threadIdx.x;
  int v = (t < nb) ? partials[t] : 0;
  sh[t] = v;
  __syncthreads();
  for (int off = 1; off < 1024; off <<= 1) {
    int y = (t >= off) ? sh[t - off] : 0;
    __syncthreads();
    sh[t] += y;
    __syncthreads();
  }
  if (t < nb) partials[t] = sh[t] - v;  // exclusive
}

__global__ void add_offsets(int* __restrict__ rp, int* __restrict__ cursor,
                            const int* __restrict__ partials, int n, int total) {
  int i = blockIdx.x * 256 + threadIdx.x;
  if (i < n) {
    int v = rp[i] + partials[i >> 8];
    rp[i] = v;
    cursor[i] = v;
  }
  if (i == 0) rp[n] = total;
}

__global__ void fill_csr(const int* __restrict__ dst, const int* __restrict__ src,
                         int* __restrict__ cursor, int* __restrict__ eidx, int n) {
  int stride = gridDim.x * blockDim.x;
  for (int i = blockIdx.x * blockDim.x + threadIdx.x; i < n; i += stride) {
    int d = dst[i];
    int pos = atomicAdd(&cursor[d], 1);
    eidx[pos] = src[i];
  }
}

// ---------------------------------------------------------------- mean pull
// one wave per destination node; lane handles 2 of 128 cols
__launch_bounds__(256)
__global__ void pull_mean(const float* __restrict__ xsrc, const int* __restrict__ rp,
                          const int* __restrict__ eidx, float* __restrict__ agg, int ndst) {
  int wid = (int)((blockIdx.x * (unsigned)blockDim.x + threadIdx.x) >> 6);
  int lane = threadIdx.x & 63;
  if (wid >= ndst) return;
  int s = rp[wid], e = rp[wid + 1];
  float ax = 0.f, ay = 0.f;
  for (int i = s; i < e; ++i) {
    int src = eidx[i];
    const float2 v = *(const float2*)(xsrc + (size_t)src * HD + lane * 2);
    ax += v.x;
    ay += v.y;
  }
  float inv = (e > s) ? 1.0f / (float)(e - s) : 0.0f;
  float2 o;
  o.x = ax * inv;
  o.y = ay * inv;
  *(float2*)(agg + (size_t)wid * HD + lane * 2) = o;
}

// ---------------------------------------------------------------- GEMM
// out[n][h] = bias[h] + sum_k A1[n][k]*W1[h][k] (+ sum_k A2[n][k]*W2[h][k])
// 128-row tile x 128 cols, 256 threads (16x16), 8x8 microtile, K-tile = 16.
// Safe when out aliases A1 (all A1 reads of a block's row-tile complete before
// the barrier that precedes this block's stores; row tiles are disjoint).
__device__ __forceinline__ void load_tileT(float* tile, const float* src, int r0, int k0,
                                           int ldk, int nrows, int t) {
  // [128 rows][16 k] -> transposed tile[k][row], row stride 132 floats
#pragma unroll
  for (int it = 0; it < 2; ++it) {
    int if4 = t + it * 256;
    int row = if4 >> 2;
    int kc = (if4 & 3) << 2;
    float4 v = make_float4(0.f, 0.f, 0.f, 0.f);
    int gr = r0 + row;
    if (gr < nrows) v = *(const float4*)(src + (size_t)gr * ldk + k0 + kc);
    tile[(kc + 0) * 132 + row] = v.x;
    tile[(kc + 1) * 132 + row] = v.y;
    tile[(kc + 2) * 132 + row] = v.z;
    tile[(kc + 3) * 132 + row] = v.w;
  }
}

template <int K, bool DUAL>
__launch_bounds__(256)
__global__ void gemm_kernel(const float* A1, const float* W1, const float* A2,
                            const float* W2, const float* bias, float* out, int N) {
  __shared__ __attribute__((aligned(16))) float sA1[16 * 132];
  __shared__ __attribute__((aligned(16))) float sW1[16 * 132];
  __shared__ __attribute__((aligned(16))) float sA2[DUAL ? 16 * 132 : 4];
  __shared__ __attribute__((aligned(16))) float sW2[DUAL ? 16 * 132 : 4];
  const int t = threadIdx.x;
  const int tx = t & 15, ty = t >> 4;
  const int r0 = blockIdx.x * 128;

  float acc[8][8];
#pragma unroll
  for (int i = 0; i < 8; ++i)
#pragma unroll
    for (int j = 0; j < 8; ++j) acc[i][j] = 0.f;

  for (int k0 = 0; k0 < K; k0 += 16) {
    if (k0) __syncthreads();
    load_tileT(sA1, A1, r0, k0, K, N, t);
    load_tileT(sW1, W1, 0, k0, K, HD, t);
    if constexpr (DUAL) {
      load_tileT(sA2, A2, r0, k0, K, N, t);
      load_tileT(sW2, W2, 0, k0, K, HD, t);
    }
    __syncthreads();
#pragma unroll
    for (int kk = 0; kk < 16; ++kk) {
      float af[8], wf[8];
      *(float4*)&af[0] = *(const float4*)&sA1[kk * 132 + ty * 4];
      *(float4*)&af[4] = *(const float4*)&sA1[kk * 132 + 64 + ty * 4];
      *(float4*)&wf[0] = *(const float4*)&sW1[kk * 132 + tx * 4];
      *(float4*)&wf[4] = *(const float4*)&sW1[kk * 132 + 64 + tx * 4];
#pragma unroll
      for (int i = 0; i < 8; ++i)
#pragma unroll
        for (int j = 0; j < 8; ++j) acc[i][j] = fmaf(af[i], wf[j], acc[i][j]);
      if constexpr (DUAL) {
        *(float4*)&af[0] = *(const float4*)&sA2[kk * 132 + ty * 4];
        *(float4*)&af[4] = *(const float4*)&sA2[kk * 132 + 64 + ty * 4];
        *(float4*)&wf[0] = *(const float4*)&sW2[kk * 132 + tx * 4];
        *(float4*)&wf[4] = *(const float4*)&sW2[kk * 132 + 64 + tx * 4];
#pragma unroll
        for (int i = 0; i < 8; ++i)
#pragma unroll
          for (int j = 0; j < 8; ++j) acc[i][j] = fmaf(af[i], wf[j], acc[i][j]);
      }
    }
  }

  float4 b0 = *(const float4*)&bias[tx * 4];
  float4 b1 = *(const float4*)&bias[64 + tx * 4];
#pragma unroll
  for (int ih = 0; ih < 2; ++ih)
#pragma unroll
    for (int ii = 0; ii < 4; ++ii) {
      int r = r0 + ih * 64 + ty * 4 + ii;
      if (r < N) {
        int i = ih * 4 + ii;
        float4 o0 = make_float4(acc[i][0] + b0.x, acc[i][1] + b0.y, acc[i][2] + b0.z,
                                acc[i][3] + b0.w);
        float4 o1 = make_float4(acc[i][4] + b1.x, acc[i][5] + b1.y, acc[i][6] + b1.z,
                                acc[i][7] + b1.w);
        *(float4*)(out + (size_t)r * HD + tx * 4) = o0;
        *(float4*)(out + (size_t)r * HD + 64 + tx * 4) = o1;
      }
    }
}

// ---------------------------------------------------------------- batch norm
__global__ void bn_stats(const float* __restrict__ x, float* __restrict__ stats, int N) {
  __shared__ float red[512];
  int t = threadIdx.x;
  int c = t & 127, half = t >> 7;
  float s = 0.f, s2 = 0.f;
  for (int row = blockIdx.x * 2 + half; row < N; row += gridDim.x * 2) {
    float v = x[(size_t)row * HD + c];
    s += v;
    s2 = fmaf(v, v, s2);
  }
  red[t] = s;
  red[256 + t] = s2;
  __syncthreads();
  if (t < 128) {
    s = red[t] + red[t + 128];
    s2 = red[256 + t] + red[256 + t + 128];
    atomicAdd(&stats[c], s);
    atomicAdd(&stats[128 + c], s2);
  }
}

__global__ void bn_final(const float* __restrict__ stats, const float* __restrict__ g,
                         const float* __restrict__ b, float* __restrict__ ss, int N) {
  int c = threadIdx.x;
  float invN = 1.0f / (float)N;
  float m = stats[c] * invN;
  float v = fmaf(-m, m, stats[128 + c] * invN);
  v = v < 0.f ? 0.f : v;
  float sc = g[c] * rsqrtf(v + 1e-5f);
  ss[c] = sc;
  ss[128 + c] = fmaf(-m, sc, b[c]);
}

__global__ void bn_apply_relu(const float* __restrict__ x, const float* __restrict__ ss,
                              float* __restrict__ y, int n4) {
  int i = blockIdx.x * blockDim.x + threadIdx.x;
  if (i >= n4) return;
  int cg = (i & 31) * 4;
  float4 v = *(const float4*)(x + (size_t)i * 4);
  float4 sc = *(const float4*)(ss + cg);
  float4 sh = *(const float4*)(ss + 128 + cg);
  float4 o;
  o.x = fmaxf(fmaf(v.x, sc.x, sh.x), 0.f);
  o.y = fmaxf(fmaf(v.y, sc.y, sh.y), 0.f);
  o.z = fmaxf(fmaf(v.z, sc.z, sh.z), 0.f);
  o.w = fmaxf(fmaf(v.w, sc.w, sh.w), 0.f);
  *(float4*)(y + (size_t)i * 4) = o;
}

// ---------------------------------------------------------------- launch
extern "C" void kernel_launch(void* const* d_in, const int* in_sizes, int n_in,
                              void* d_out, int out_size, void* d_ws, size_t ws_size,
                              hipStream_t stream) {
  const float* x_user = (const float*)d_in[0];
  const float* x_event = (const float*)d_in[1];
  const int* edge_user = (const int*)d_in[2];
  const int* edge_event = (const int*)d_in[3];
  const float* up_W = (const float*)d_in[4];
  const float* up_b = (const float*)d_in[5];
  const float* ep_W = (const float*)d_in[6];
  const float* ep_b = (const float*)d_in[7];
  const float* u_Wl = (const float*)d_in[8];
  const float* u_bl = (const float*)d_in[9];
  const float* u_Wr = (const float*)d_in[10];
  const float* u_bng = (const float*)d_in[11];
  const float* u_bnb = (const float*)d_in[12];
  const float* e_Wl = (const float*)d_in[13];
  const float* e_bl = (const float*)d_in[14];
  const float* e_Wr = (const float*)d_in[15];
  const float* e_bng = (const float*)d_in[16];
  const float* e_bnb = (const float*)d_in[17];
  (void)in_sizes; (void)n_in; (void)out_size; (void)ws_size;
  (void)u_bng; (void)u_bnb; (void)e_bng; (void)e_bnb;

  float* xu = (float*)d_out;                  // [NUSER][128]
  float* xe = xu + (size_t)NUSER * HD;        // [NEVENT][128]

  char* w = (char*)d_ws;
  float* agg = (float*)w;  w += (size_t)NUSER * HD * 4;   // 102.4 MB (also GEMM out)
  int* rp_u = (int*)w;     w += ((size_t)NUSER + 64) * 4;
  int* cur_u = (int*)w;    w += (size_t)NUSER * 4;
  int* ei_u = (int*)w;     w += (size_t)NEDGE * 4;
  int* rp_e = (int*)w;     w += ((size_t)NEVENT + 64) * 4;
  int* cur_e = (int*)w;    w += (size_t)NEVENT * 4;
  int* ei_e = (int*)w;     w += (size_t)NEDGE * 4;
  int* part = (int*)w;     w += 4096 * 4;
  float* stats = (float*)w; w += 256 * 4;
  float* ss = (float*)w;    w += 256 * 4;

  // ---- CSR build (both directions), reused by both layers
  hipMemsetAsync(cur_u, 0, (size_t)NUSER * 4, stream);
  hipMemsetAsync(cur_e, 0, (size_t)NEVENT * 4, stream);
  count_edges<<<2048, 256, 0, stream>>>(edge_user, cur_u, NEDGE);
  count_edges<<<2048, 256, 0, stream>>>(edge_event, cur_e, NEDGE);
  int nbu = (NUSER + 255) / 256;   // 782  (<=1024 for scan_partials)
  int nbe = (NEVENT + 255) / 256;  // 196
  scan_blocks<<<nbu, 256, 0, stream>>>(cur_u, rp_u, part, NUSER);
  scan_partials<<<1, 1024, 0, stream>>>(part, nbu);
  add_offsets<<<nbu, 256, 0, stream>>>(rp_u, cur_u, part, NUSER, NEDGE);
  scan_blocks<<<nbe, 256, 0, stream>>>(cur_e, rp_e, part, NEVENT);
  scan_partials<<<1, 1024, 0, stream>>>(part, nbe);
  add_offsets<<<nbe, 256, 0, stream>>>(rp_e, cur_e, part, NEVENT, NEDGE);
  fill_csr<<<2048, 256, 0, stream>>>(edge_user, edge_event, cur_u, ei_u, NEDGE);
  fill_csr<<<2048, 256, 0, stream>>>(edge_event, edge_user, cur_e, ei_e, NEDGE);

  // ---- initial projections
  gemm_kernel<FIN, false><<<(NUSER + 127) / 128, 256, 0, stream>>>(
      x_user, up_W, nullptr, nullptr, up_b, xu, NUSER);
  gemm_kernel<FIN, false><<<(NEVENT + 127) / 128, 256, 0, stream>>>(
      x_event, ep_W, nullptr, nullptr, ep_b, xe, NEVENT);

  // ---- layers
  for (int l = 0; l < NLAYER; ++l) {
    // event -> user
    pull_mean<<<(NUSER * 64) / 256, 256, 0, stream>>>(xe, rp_u, ei_u, agg, NUSER);
    gemm_kernel<HD, true><<<(NUSER + 127) / 128, 256, 0, stream>>>(
        agg, u_Wl + (size_t)l * HD * HD, xu, u_Wr + (size_t)l * HD * HD,
        u_bl + (size_t)l * HD, agg, NUSER);
    hipMemsetAsync(stats, 0, 256 * 4, stream);
    bn_stats<<<1024, 256, 0, stream>>>(agg, stats, NUSER);
    bn_final<<<1, 128, 0, stream>>>(stats, u_bng + (size_t)l * HD, u_bnb + (size_t)l * HD,
                                    ss, NUSER);
    bn_apply_relu<<<(NUSER * 32 + 255) / 256, 256, 0, stream>>>(agg, ss, xu, NUSER * 32);
    // user -> event
    pull_mean<<<(NEVENT * 64) / 256, 256, 0, stream>>>(xu, rp_e, ei_e, agg, NEVENT);
    gemm_kernel<HD, true><<<(NEVENT + 127) / 128, 256, 0, stream>>>(
        agg, e_Wl + (size_t)l * HD * HD, xe, e_Wr + (size_t)l * HD * HD,
        e_bl + (size_t)l * HD, agg, NEVENT);
    hipMemsetAsync(stats, 0, 256 * 4, stream);
    bn_stats<<<1024, 256, 0, stream>>>(agg, stats, NEVENT);
    bn_final<<<1, 128, 0, stream>>>(stats, e_bng + (size_t)l * HD, e_bnb + (size_t)l * HD,
                                    ss, NEVENT);
    bn_apply_relu<<<(NEVENT * 32 + 255) / 256, 256, 0, stream>>>(agg, ss, xe, NEVENT * 32);
  }
}

// Round 4
// 1885.843 us; speedup vs baseline: 1.3603x; 1.3603x over previous
//
#include <hip/hip_runtime.h>
#include <hip/hip_bf16.h>

#define NUSER 200000
#define NEVENT 50000
#define NEDGE 2000000
#define FU 256
#define HD 128
#define NLAYER 2

typedef __attribute__((ext_vector_type(8))) short short8;
typedef __attribute__((ext_vector_type(4))) float f32x4;

__device__ __forceinline__ float bf2f(unsigned int u16) {
  union { unsigned int i; float f; } x;
  x.i = u16 << 16;
  return x.f;
}
__device__ __forceinline__ unsigned short f2bf(float f) {
  union { float f; unsigned int i; } x;
  x.f = f;
  unsigned int r = x.i + 0x7fffu + ((x.i >> 16) & 1u);
  return (unsigned short)(r >> 16);
}

// ---------------------------------------------------------------- CSR build
__global__ void count_edges(const int* __restrict__ dst, int* __restrict__ cnt, int n) {
  int stride = gridDim.x * blockDim.x;
  for (int i = blockIdx.x * blockDim.x + threadIdx.x; i < n; i += stride)
    atomicAdd(&cnt[dst[i]], 1);
}

__global__ void scan_blocks(const int* __restrict__ cnt, int* __restrict__ excl,
                            int* __restrict__ partials, int n) {
  __shared__ int sh[256];
  int t = threadIdx.x;
  int i = blockIdx.x * 256 + t;
  int v = (i < n) ? cnt[i] : 0;
  sh[t] = v;
  __syncthreads();
  for (int off = 1; off < 256; off <<= 1) {
    int y = (t >= off) ? sh[t - off] : 0;
    __syncthreads();
    sh[t] += y;
    __syncthreads();
  }
  if (i < n) excl[i] = sh[t] - v;
  if (t == 255) partials[blockIdx.x] = sh[255];
}

__global__ void scan_partials(int* __restrict__ partials, int nb) {
  __shared__ int sh[1024];
  int t = threadIdx.x;
  int v = (t < nb) ? partials[t] : 0;
  sh[t] = v;
  __syncthreads();
  for (int off = 1; off < 1024; off <<= 1) {
    int y = (t >= off) ? sh[t - off] : 0;
    __syncthreads();
    sh[t] += y;
    __syncthreads();
  }
  if (t < nb) partials[t] = sh[t] - v;  // exclusive
}

__global__ void add_offsets(int* __restrict__ rp, int* __restrict__ cursor,
                            const int* __restrict__ partials, int n, int total) {
  int i = blockIdx.x * 256 + threadIdx.x;
  if (i < n) {
    int v = rp[i] + partials[i >> 8];
    rp[i] = v;
    cursor[i] = v;
  }
  if (i == 0) rp[n] = total;
}

__global__ void fill_csr(const int* __restrict__ dst, const int* __restrict__ src,
                         int* __restrict__ cursor, int* __restrict__ eidx, int n) {
  int stride = gridDim.x * blockDim.x;
  for (int i = blockIdx.x * blockDim.x + threadIdx.x; i < n; i += stride) {
    int d = dst[i];
    int pos = atomicAdd(&cursor[d], 1);
    eidx[pos] = src[i];
  }
}

// ---------------------------------------------------------------- weights -> bf16
// six 32768-element matrices concatenated
__global__ void conv_weights(const float* __restrict__ s0, const float* __restrict__ s1,
                             const float* __restrict__ s2, const float* __restrict__ s3,
                             const float* __restrict__ s4, const float* __restrict__ s5,
                             unsigned short* __restrict__ dst) {
  int idx = blockIdx.x * 256 + threadIdx.x;  // 6*32768 total
  int sel = idx >> 15, off = idx & 32767;
  const float* p = sel == 0 ? s0 : sel == 1 ? s1 : sel == 2 ? s2 : sel == 3 ? s3 : sel == 4 ? s4 : s5;
  dst[idx] = f2bf(p[off]);
}

// ---------------------------------------------------------------- mean pull (bf16)
// one wave per destination node; lane handles 2 of 128 cols (4B per lane)
__launch_bounds__(256)
__global__ void pull_mean_bf(const unsigned short* __restrict__ xsrc, const int* __restrict__ rp,
                             const int* __restrict__ eidx, unsigned short* __restrict__ agg,
                             int ndst) {
  int wid = (int)((blockIdx.x * 256u + threadIdx.x) >> 6);
  int lane = threadIdx.x & 63;
  if (wid >= ndst) return;
  int s = rp[wid], e = rp[wid + 1];
  float ax = 0.f, ay = 0.f;
  for (int i = s; i < e; ++i) {
    int src = eidx[i];
    unsigned int v = *(const unsigned int*)(xsrc + (size_t)src * HD + lane * 2);
    ax += bf2f(v & 0xffffu);
    ay += bf2f(v >> 16);
  }
  float inv = (e > s) ? 1.0f / (float)(e - s) : 0.0f;
  unsigned int o = (unsigned int)f2bf(ax * inv) | ((unsigned int)f2bf(ay * inv) << 16);
  *(unsigned int*)(agg + (size_t)wid * HD + lane * 2) = o;
}

// ---------------------------------------------------------------- MFMA GEMM
// out[n][h] = bias[h] + sum_k A1[n][k]*W1[h][k] (+ A2[n][k]*W2[h][k])
// BM=128, BN=128(=HD), 256 threads = 4 waves (2x2), each wave 64x64 via 4x4
// mfma_f32_16x16x32_bf16 fragments. A tiles staged in LDS with 16B-slot XOR
// swizzle (G4); W fragments read from L2-hot global bf16. Optional fused
// BN partial stats (sum, sumsq per column) -> 32-replica global atomics.
// Safe when outb aliases A1 (block reads only its own rows, before stores).
template <int K, bool AFP32, bool DUAL, bool FUSE_BN>
__launch_bounds__(256)
__global__ void gemm_mfma(const void* __restrict__ A1v, const unsigned short* __restrict__ W1,
                          const unsigned short* __restrict__ A2,
                          const unsigned short* __restrict__ W2,
                          const float* __restrict__ bias, unsigned short* __restrict__ outb,
                          float* __restrict__ stats, int N) {
  __shared__ unsigned short sA[32768];  // 64 KB (one K=256 tile, or two K=128 tiles)
  const int tid = threadIdx.x;
  const int r0 = blockIdx.x * 128;

  // ---- stage A tile(s) into LDS
  if constexpr (AFP32) {
    const float* A = (const float*)A1v;
    const int CPR = K / 8;  // 16B chunks per row
    for (int c = tid; c < 128 * CPR; c += 256) {
      int row = c / CPR, slot = c % CPR;
      int grow = r0 + row;
      float4 v0 = {0.f, 0.f, 0.f, 0.f}, v1 = {0.f, 0.f, 0.f, 0.f};
      if (grow < N) {
        const float4* p = (const float4*)(A + (size_t)grow * K + slot * 8);
        v0 = p[0];
        v1 = p[1];
      }
      uint4 u;
      u.x = (unsigned)f2bf(v0.x) | ((unsigned)f2bf(v0.y) << 16);
      u.y = (unsigned)f2bf(v0.z) | ((unsigned)f2bf(v0.w) << 16);
      u.z = (unsigned)f2bf(v1.x) | ((unsigned)f2bf(v1.y) << 16);
      u.w = (unsigned)f2bf(v1.z) | ((unsigned)f2bf(v1.w) << 16);
      int baddr = row * (K * 2) + ((slot * 16) ^ ((row & 7) << 4));
      *(uint4*)((char*)sA + baddr) = u;
    }
  } else {
    const unsigned short* A = (const unsigned short*)A1v;
    const int CPR = K / 8;
    const int NC = 128 * CPR;
    for (int c = tid; c < NC * (DUAL ? 2 : 1); c += 256) {
      int cc = c;
      const unsigned short* src = A;
      unsigned short* dstp = sA;
      if (DUAL && cc >= NC) {
        cc -= NC;
        src = A2;
        dstp = sA + 16384;
      }
      int row = cc / CPR, slot = cc % CPR;
      int grow = r0 + row;
      uint4 u = {0u, 0u, 0u, 0u};
      if (grow < N) u = *(const uint4*)(src + (size_t)grow * K + slot * 8);
      int baddr = row * (K * 2) + ((slot * 16) ^ ((row & 7) << 4));
      *(uint4*)((char*)dstp + baddr) = u;
    }
  }
  __syncthreads();

  const int lane = tid & 63, wid = tid >> 6;
  const int wr = wid >> 1, wc = wid & 1;
  const int lr = lane & 15, lg = lane >> 4;

  f32x4 acc[4][4] = {};

#pragma unroll
  for (int ks = 0; ks < K / 32; ++ks) {
    short8 af[4], wf[4];
#pragma unroll
    for (int m = 0; m < 4; ++m) {
      int row = wr * 64 + m * 16 + lr;
      int kb = (ks * 32 + lg * 8) * 2;
      af[m] = *(const short8*)((const char*)sA + row * (K * 2) + (kb ^ ((row & 7) << 4)));
    }
#pragma unroll
    for (int n = 0; n < 4; ++n) {
      int h = wc * 64 + n * 16 + lr;
      wf[n] = *(const short8*)(W1 + (size_t)h * K + ks * 32 + lg * 8);
    }
#pragma unroll
    for (int m = 0; m < 4; ++m)
#pragma unroll
      for (int n = 0; n < 4; ++n)
        acc[m][n] = __builtin_amdgcn_mfma_f32_16x16x32_bf16(af[m], wf[n], acc[m][n], 0, 0, 0);
    if constexpr (DUAL) {
      short8 af2[4], wf2[4];
#pragma unroll
      for (int m = 0; m < 4; ++m) {
        int row = wr * 64 + m * 16 + lr;
        int kb = (ks * 32 + lg * 8) * 2;
        af2[m] = *(const short8*)((const char*)(sA + 16384) + row * (K * 2) +
                                  (kb ^ ((row & 7) << 4)));
      }
#pragma unroll
      for (int n = 0; n < 4; ++n) {
        int h = wc * 64 + n * 16 + lr;
        wf2[n] = *(const short8*)(W2 + (size_t)h * K + ks * 32 + lg * 8);
      }
#pragma unroll
      for (int m = 0; m < 4; ++m)
#pragma unroll
        for (int n = 0; n < 4; ++n)
          acc[m][n] = __builtin_amdgcn_mfma_f32_16x16x32_bf16(af2[m], wf2[n], acc[m][n], 0, 0, 0);
    }
  }
  __syncthreads();  // all waves done reading sA; reuse it for output repack

  // ---- epilogue: bias, BN partials, LDS repack -> coalesced bf16 store
  float bcol[4];
#pragma unroll
  for (int n = 0; n < 4; ++n) bcol[n] = bias[wc * 64 + n * 16 + lr];
  float sum[4] = {0.f, 0.f, 0.f, 0.f}, sq[4] = {0.f, 0.f, 0.f, 0.f};
#pragma unroll
  for (int m = 0; m < 4; ++m)
#pragma unroll
    for (int n = 0; n < 4; ++n) {
      int col = wc * 64 + n * 16 + lr;
#pragma unroll
      for (int r = 0; r < 4; ++r) {
        int row = wr * 64 + m * 16 + lg * 4 + r;
        float y = acc[m][n][r] + bcol[n];
        if constexpr (FUSE_BN) {
          if (r0 + row < N) {
            sum[n] += y;
            sq[n] = fmaf(y, y, sq[n]);
          }
        }
        int baddr = row * 256 + ((col * 2) ^ (((row >> 2) & 3) << 5));
        *(unsigned short*)((char*)sA + baddr) = f2bf(y);
      }
    }
  if constexpr (FUSE_BN) {
#pragma unroll
    for (int n = 0; n < 4; ++n) {
      sum[n] += __shfl_xor(sum[n], 16);
      sum[n] += __shfl_xor(sum[n], 32);
      sq[n] += __shfl_xor(sq[n], 16);
      sq[n] += __shfl_xor(sq[n], 32);
    }
    if (lg == 0) {
      float* st = stats + (size_t)(blockIdx.x & 31) * 256;
#pragma unroll
      for (int n = 0; n < 4; ++n) {
        int col = wc * 64 + n * 16 + lr;
        atomicAdd(&st[col], sum[n]);
        atomicAdd(&st[128 + col], sq[n]);
      }
    }
  }
  __syncthreads();
  for (int c = tid; c < 2048; c += 256) {
    int row = c >> 4, slot = c & 15;
    int grow = r0 + row;
    if (grow < N) {
      uint4 v = *(const uint4*)((const char*)sA + row * 256 +
                                ((slot * 16) ^ (((row >> 2) & 3) << 5)));
      *(uint4*)(outb + (size_t)grow * HD + slot * 8) = v;
    }
  }
}

// ---------------------------------------------------------------- batch norm tail
__global__ void bn_final_k(const float* __restrict__ stats, const float* __restrict__ g,
                           const float* __restrict__ b, float* __restrict__ ss, float invN) {
  int c = threadIdx.x;  // 128
  float s = 0.f, q = 0.f;
  for (int r = 0; r < 32; ++r) {
    s += stats[r * 256 + c];
    q += stats[r * 256 + 128 + c];
  }
  float m = s * invN;
  float v = fmaf(-m, m, q * invN);
  v = v < 0.f ? 0.f : v;
  float sc = g[c] * rsqrtf(v + 1e-5f);
  ss[c] = sc;
  ss[128 + c] = fmaf(-m, sc, b[c]);
}

__launch_bounds__(256)
__global__ void bn_apply_relu_bf(const unsigned short* __restrict__ y,
                                 const float* __restrict__ ss, unsigned short* __restrict__ xb,
                                 float* __restrict__ xf, int N) {
  int i = blockIdx.x * 256 + threadIdx.x;  // chunks of 8 bf16
  if (i >= N * 16) return;
  int row = i >> 4, cg = (i & 15) * 8;
  uint4 v = *(const uint4*)(y + (size_t)i * 8);
  float4 sc0 = *(const float4*)(ss + cg);
  float4 sc1 = *(const float4*)(ss + cg + 4);
  float4 sh0 = *(const float4*)(ss + 128 + cg);
  float4 sh1 = *(const float4*)(ss + 132 + cg);
  float o0 = fmaxf(fmaf(bf2f(v.x & 0xffffu), sc0.x, sh0.x), 0.f);
  float o1 = fmaxf(fmaf(bf2f(v.x >> 16), sc0.y, sh0.y), 0.f);
  float o2 = fmaxf(fmaf(bf2f(v.y & 0xffffu), sc0.z, sh0.z), 0.f);
  float o3 = fmaxf(fmaf(bf2f(v.y >> 16), sc0.w, sh0.w), 0.f);
  float o4 = fmaxf(fmaf(bf2f(v.z & 0xffffu), sc1.x, sh1.x), 0.f);
  float o5 = fmaxf(fmaf(bf2f(v.z >> 16), sc1.y, sh1.y), 0.f);
  float o6 = fmaxf(fmaf(bf2f(v.w & 0xffffu), sc1.z, sh1.z), 0.f);
  float o7 = fmaxf(fmaf(bf2f(v.w >> 16), sc1.w, sh1.w), 0.f);
  uint4 ob;
  ob.x = (unsigned)f2bf(o0) | ((unsigned)f2bf(o1) << 16);
  ob.y = (unsigned)f2bf(o2) | ((unsigned)f2bf(o3) << 16);
  ob.z = (unsigned)f2bf(o4) | ((unsigned)f2bf(o5) << 16);
  ob.w = (unsigned)f2bf(o6) | ((unsigned)f2bf(o7) << 16);
  *(uint4*)(xb + (size_t)i * 8) = ob;
  if (xf) {
    float4 a = {o0, o1, o2, o3};
    float4 bq = {o4, o5, o6, o7};
    *(float4*)(xf + (size_t)row * HD + cg) = a;
    *(float4*)(xf + (size_t)row * HD + cg + 4) = bq;
  }
}

// ---------------------------------------------------------------- launch
extern "C" void kernel_launch(void* const* d_in, const int* in_sizes, int n_in,
                              void* d_out, int out_size, void* d_ws, size_t ws_size,
                              hipStream_t stream) {
  const float* x_user = (const float*)d_in[0];
  const float* x_event = (const float*)d_in[1];
  const int* edge_user = (const int*)d_in[2];
  const int* edge_event = (const int*)d_in[3];
  const float* up_W = (const float*)d_in[4];
  const float* up_b = (const float*)d_in[5];
  const float* ep_W = (const float*)d_in[6];
  const float* ep_b = (const float*)d_in[7];
  const float* u_Wl = (const float*)d_in[8];
  const float* u_bl = (const float*)d_in[9];
  const float* u_Wr = (const float*)d_in[10];
  const float* u_bng = (const float*)d_in[11];
  const float* u_bnb = (const float*)d_in[12];
  const float* e_Wl = (const float*)d_in[13];
  const float* e_bl = (const float*)d_in[14];
  const float* e_Wr = (const float*)d_in[15];
  const float* e_bng = (const float*)d_in[16];
  const float* e_bnb = (const float*)d_in[17];
  (void)in_sizes; (void)n_in; (void)out_size; (void)ws_size;

  float* xu_out = (float*)d_out;                    // [NUSER][128] fp32
  float* xe_out = xu_out + (size_t)NUSER * HD;      // [NEVENT][128] fp32

  char* w = (char*)d_ws;
  unsigned short* xu_bf = (unsigned short*)w;  w += (size_t)NUSER * HD * 2;   // 51.2 MB
  unsigned short* xe_bf = (unsigned short*)w;  w += (size_t)NEVENT * HD * 2;  // 12.8 MB
  unsigned short* aggb  = (unsigned short*)w;  w += (size_t)NUSER * HD * 2;   // 51.2 MB (pull out + gemm out)
  unsigned short* wbf   = (unsigned short*)w;  w += (size_t)196608 * 2;       // 384 KB
  int* rp_u  = (int*)w;  w += ((size_t)NUSER + 64) * 4;
  int* cur_u = (int*)w;  w += (size_t)NUSER * 4;
  int* ei_u  = (int*)w;  w += (size_t)NEDGE * 4;
  int* rp_e  = (int*)w;  w += ((size_t)NEVENT + 64) * 4;
  int* cur_e = (int*)w;  w += (size_t)NEVENT * 4;
  int* ei_e  = (int*)w;  w += (size_t)NEDGE * 4;
  int* part  = (int*)w;  w += 4096 * 4;
  float* stats = (float*)w;  w += (size_t)4 * 32 * 256 * 4;  // 4 regions x 32 replicas x 256
  float* ss = (float*)w;     w += 256 * 4;

  const unsigned short* wb_up = wbf;
  const unsigned short* wb_ep = wbf + 32768;
  const unsigned short* wb_uWl = wbf + 65536;
  const unsigned short* wb_uWr = wbf + 98304;
  const unsigned short* wb_eWl = wbf + 131072;
  const unsigned short* wb_eWr = wbf + 163840;

  // ---- CSR build (both directions), reused by both layers
  hipMemsetAsync(cur_u, 0, (size_t)NUSER * 4, stream);
  hipMemsetAsync(cur_e, 0, (size_t)NEVENT * 4, stream);
  hipMemsetAsync(stats, 0, (size_t)4 * 32 * 256 * 4, stream);
  count_edges<<<2048, 256, 0, stream>>>(edge_user, cur_u, NEDGE);
  count_edges<<<2048, 256, 0, stream>>>(edge_event, cur_e, NEDGE);
  int nbu = (NUSER + 255) / 256;   // 782
  int nbe = (NEVENT + 255) / 256;  // 196
  scan_blocks<<<nbu, 256, 0, stream>>>(cur_u, rp_u, part, NUSER);
  scan_partials<<<1, 1024, 0, stream>>>(part, nbu);
  add_offsets<<<nbu, 256, 0, stream>>>(rp_u, cur_u, part, NUSER, NEDGE);
  scan_blocks<<<nbe, 256, 0, stream>>>(cur_e, rp_e, part, NEVENT);
  scan_partials<<<1, 1024, 0, stream>>>(part, nbe);
  add_offsets<<<nbe, 256, 0, stream>>>(rp_e, cur_e, part, NEVENT, NEDGE);
  fill_csr<<<2048, 256, 0, stream>>>(edge_user, edge_event, cur_u, ei_u, NEDGE);
  fill_csr<<<2048, 256, 0, stream>>>(edge_event, edge_user, cur_e, ei_e, NEDGE);

  // ---- weights -> bf16
  conv_weights<<<768, 256, 0, stream>>>(up_W, ep_W, u_Wl, u_Wr, e_Wl, e_Wr, wbf);

  // ---- initial projections (fp32 in, bf16 MFMA, bf16 out)
  int gbu = (NUSER + 127) / 128, gbe = (NEVENT + 127) / 128;
  gemm_mfma<FU, true, false, false><<<gbu, 256, 0, stream>>>(
      x_user, wb_up, nullptr, nullptr, up_b, xu_bf, nullptr, NUSER);
  gemm_mfma<FU, true, false, false><<<gbe, 256, 0, stream>>>(
      x_event, wb_ep, nullptr, nullptr, ep_b, xe_bf, nullptr, NEVENT);

  // ---- layers
  for (int l = 0; l < NLAYER; ++l) {
    float* stU = stats + (size_t)(l * 2 + 0) * 32 * 256;
    float* stE = stats + (size_t)(l * 2 + 1) * 32 * 256;
    // event -> user
    pull_mean_bf<<<NUSER / 4, 256, 0, stream>>>(xe_bf, rp_u, ei_u, aggb, NUSER);
    gemm_mfma<HD, false, true, true><<<gbu, 256, 0, stream>>>(
        aggb, wb_uWl + (size_t)l * HD * HD, xu_bf, wb_uWr + (size_t)l * HD * HD,
        u_bl + (size_t)l * HD, aggb, stU, NUSER);
    bn_final_k<<<1, 128, 0, stream>>>(stU, u_bng + (size_t)l * HD, u_bnb + (size_t)l * HD,
                                      ss, 1.0f / (float)NUSER);
    bn_apply_relu_bf<<<(NUSER * 16 + 255) / 256, 256, 0, stream>>>(
        aggb, ss, xu_bf, (l == NLAYER - 1) ? xu_out : nullptr, NUSER);
    // user -> event
    pull_mean_bf<<<NEVENT / 4, 256, 0, stream>>>(xu_bf, rp_e, ei_e, aggb, NEVENT);
    gemm_mfma<HD, false, true, true><<<gbe, 256, 0, stream>>>(
        aggb, wb_eWl + (size_t)l * HD * HD, xe_bf, wb_eWr + (size_t)l * HD * HD,
        e_bl + (size_t)l * HD, aggb, stE, NEVENT);
    bn_final_k<<<1, 128, 0, stream>>>(stE, e_bng + (size_t)l * HD, e_bnb + (size_t)l * HD,
                                      ss, 1.0f / (float)NEVENT);
    bn_apply_relu_bf<<<(NEVENT * 16 + 255) / 256, 256, 0, stream>>>(
        aggb, ss, xe_bf, (l == NLAYER - 1) ? xe_out : nullptr, NEVENT);
  }
}

// Round 5
// 1504.281 us; speedup vs baseline: 1.7053x; 1.2537x over previous
//
#include <hip/hip_runtime.h>
#include <hip/hip_bf16.h>

#define NUSER 200000
#define NEVENT 50000
#define NEDGE 2000000
#define FU 256
#define HD 128
#define NLAYER 2

typedef __attribute__((ext_vector_type(8))) short short8;
typedef __attribute__((ext_vector_type(4))) float f32x4;

__device__ __forceinline__ float bf2f(unsigned int u16) {
  union { unsigned int i; float f; } x;
  x.i = u16 << 16;
  return x.f;
}
__device__ __forceinline__ unsigned short f2bf(float f) {
  union { float f; unsigned int i; } x;
  x.f = f;
  unsigned int r = x.i + 0x7fffu + ((x.i >> 16) & 1u);
  return (unsigned short)(r >> 16);
}

// ---------------------------------------------------------------- CSR build
__global__ void count_edges(const int* __restrict__ dst, int* __restrict__ cnt, int n) {
  int stride = gridDim.x * blockDim.x;
  for (int i = blockIdx.x * blockDim.x + threadIdx.x; i < n; i += stride)
    atomicAdd(&cnt[dst[i]], 1);
}

__global__ void scan_blocks(const int* __restrict__ cnt, int* __restrict__ excl,
                            int* __restrict__ partials, int n) {
  __shared__ int sh[256];
  int t = threadIdx.x;
  int i = blockIdx.x * 256 + t;
  int v = (i < n) ? cnt[i] : 0;
  sh[t] = v;
  __syncthreads();
  for (int off = 1; off < 256; off <<= 1) {
    int y = (t >= off) ? sh[t - off] : 0;
    __syncthreads();
    sh[t] += y;
    __syncthreads();
  }
  if (i < n) excl[i] = sh[t] - v;
  if (t == 255) partials[blockIdx.x] = sh[255];
}

__global__ void scan_partials(int* __restrict__ partials, int nb) {
  __shared__ int sh[1024];
  int t = threadIdx.x;
  int v = (t < nb) ? partials[t] : 0;
  sh[t] = v;
  __syncthreads();
  for (int off = 1; off < 1024; off <<= 1) {
    int y = (t >= off) ? sh[t - off] : 0;
    __syncthreads();
    sh[t] += y;
    __syncthreads();
  }
  if (t < nb) partials[t] = sh[t] - v;  // exclusive
}

__global__ void add_offsets(int* __restrict__ rp, int* __restrict__ cursor,
                            const int* __restrict__ partials, int n, int total) {
  int i = blockIdx.x * 256 + threadIdx.x;
  if (i < n) {
    int v = rp[i] + partials[i >> 8];
    rp[i] = v;
    cursor[i] = v;
  }
  if (i == 0) rp[n] = total;
}

__global__ void fill_csr(const int* __restrict__ dst, const int* __restrict__ src,
                         int* __restrict__ cursor, int* __restrict__ eidx, int n) {
  int stride = gridDim.x * blockDim.x;
  for (int i = blockIdx.x * blockDim.x + threadIdx.x; i < n; i += stride) {
    int d = dst[i];
    int pos = atomicAdd(&cursor[d], 1);
    eidx[pos] = src[i];
  }
}

// ---------------------------------------------------------------- weights -> bf16
// six 32768-element matrices concatenated
__global__ void conv_weights(const float* __restrict__ s0, const float* __restrict__ s1,
                             const float* __restrict__ s2, const float* __restrict__ s3,
                             const float* __restrict__ s4, const float* __restrict__ s5,
                             unsigned short* __restrict__ dst) {
  int idx = blockIdx.x * 256 + threadIdx.x;  // 6*32768 total
  int sel = idx >> 15, off = idx & 32767;
  const float* p = sel == 0 ? s0 : sel == 1 ? s1 : sel == 2 ? s2 : sel == 3 ? s3 : sel == 4 ? s4 : s5;
  dst[idx] = f2bf(p[off]);
}

// ---------------------------------------------------------------- mean pull (bf16)
// one wave per destination node; 16 lanes x 16B cover the 256B row, the wave's
// 4 16-lane slots process 4 edges per iteration (4 gathers in flight -> MLP 4,
// 4x fewer dependent loop trips than the 4B/lane serial version).
__launch_bounds__(256)
__global__ void pull_mean_bf(const unsigned short* __restrict__ xsrc, const int* __restrict__ rp,
                             const int* __restrict__ eidx, unsigned short* __restrict__ agg,
                             int ndst) {
  int wid = (int)((blockIdx.x * 256u + threadIdx.x) >> 6);
  int lane = threadIdx.x & 63;
  if (wid >= ndst) return;
  int s = rp[wid], e = rp[wid + 1];
  const int slot = lane >> 4;   // 0..3: which edge of the 4-edge group
  const int col8 = lane & 15;   // which 16B chunk of the 256B row
  float a0 = 0.f, a1 = 0.f, a2 = 0.f, a3 = 0.f, a4 = 0.f, a5 = 0.f, a6 = 0.f, a7 = 0.f;
  for (int base = s; base < e; base += 4) {
    int i = base + slot;
    if (i < e) {
      int row = eidx[i];
      uint4 v = *(const uint4*)(xsrc + (size_t)row * HD + col8 * 8);
      a0 += bf2f(v.x & 0xffffu);
      a1 += bf2f(v.x >> 16);
      a2 += bf2f(v.y & 0xffffu);
      a3 += bf2f(v.y >> 16);
      a4 += bf2f(v.z & 0xffffu);
      a5 += bf2f(v.z >> 16);
      a6 += bf2f(v.w & 0xffffu);
      a7 += bf2f(v.w >> 16);
    }
  }
  // reduce across the 4 slots (lanes l, l+16, l+32, l+48 hold the same columns)
  a0 += __shfl_xor(a0, 16); a0 += __shfl_xor(a0, 32);
  a1 += __shfl_xor(a1, 16); a1 += __shfl_xor(a1, 32);
  a2 += __shfl_xor(a2, 16); a2 += __shfl_xor(a2, 32);
  a3 += __shfl_xor(a3, 16); a3 += __shfl_xor(a3, 32);
  a4 += __shfl_xor(a4, 16); a4 += __shfl_xor(a4, 32);
  a5 += __shfl_xor(a5, 16); a5 += __shfl_xor(a5, 32);
  a6 += __shfl_xor(a6, 16); a6 += __shfl_xor(a6, 32);
  a7 += __shfl_xor(a7, 16); a7 += __shfl_xor(a7, 32);
  float inv = (e > s) ? 1.0f / (float)(e - s) : 0.0f;
  if (slot == 0) {
    uint4 o;
    o.x = (unsigned)f2bf(a0 * inv) | ((unsigned)f2bf(a1 * inv) << 16);
    o.y = (unsigned)f2bf(a2 * inv) | ((unsigned)f2bf(a3 * inv) << 16);
    o.z = (unsigned)f2bf(a4 * inv) | ((unsigned)f2bf(a5 * inv) << 16);
    o.w = (unsigned)f2bf(a6 * inv) | ((unsigned)f2bf(a7 * inv) << 16);
    *(uint4*)(agg + (size_t)wid * HD + col8 * 8) = o;
  }
}

// ---------------------------------------------------------------- MFMA GEMM
// out[n][h] = bias[h] + sum_k A1[n][k]*W1[h][k] (+ A2[n][k]*W2[h][k])
// BM=128, BN=128(=HD), 256 threads = 4 waves (2x2), each wave 64x64 via 4x4
// mfma_f32_16x16x32_bf16 fragments. A tiles staged in LDS with 16B-slot XOR
// swizzle (G4); W fragments read from L2-hot global bf16. Optional fused
// BN partial stats (sum, sumsq per column) -> 32-replica global atomics.
// Safe when outb aliases A1 (block reads only its own rows, before stores).
template <int K, bool AFP32, bool DUAL, bool FUSE_BN>
__launch_bounds__(256)
__global__ void gemm_mfma(const void* __restrict__ A1v, const unsigned short* __restrict__ W1,
                          const unsigned short* __restrict__ A2,
                          const unsigned short* __restrict__ W2,
                          const float* __restrict__ bias, unsigned short* __restrict__ outb,
                          float* __restrict__ stats, int N) {
  __shared__ unsigned short sA[32768];  // 64 KB (one K=256 tile, or two K=128 tiles)
  const int tid = threadIdx.x;
  const int r0 = blockIdx.x * 128;

  // ---- stage A tile(s) into LDS
  if constexpr (AFP32) {
    const float* A = (const float*)A1v;
    const int CPR = K / 8;  // 16B chunks per row
    for (int c = tid; c < 128 * CPR; c += 256) {
      int row = c / CPR, slot = c % CPR;
      int grow = r0 + row;
      float4 v0 = {0.f, 0.f, 0.f, 0.f}, v1 = {0.f, 0.f, 0.f, 0.f};
      if (grow < N) {
        const float4* p = (const float4*)(A + (size_t)grow * K + slot * 8);
        v0 = p[0];
        v1 = p[1];
      }
      uint4 u;
      u.x = (unsigned)f2bf(v0.x) | ((unsigned)f2bf(v0.y) << 16);
      u.y = (unsigned)f2bf(v0.z) | ((unsigned)f2bf(v0.w) << 16);
      u.z = (unsigned)f2bf(v1.x) | ((unsigned)f2bf(v1.y) << 16);
      u.w = (unsigned)f2bf(v1.z) | ((unsigned)f2bf(v1.w) << 16);
      int baddr = row * (K * 2) + ((slot * 16) ^ ((row & 7) << 4));
      *(uint4*)((char*)sA + baddr) = u;
    }
  } else {
    const unsigned short* A = (const unsigned short*)A1v;
    const int CPR = K / 8;
    const int NC = 128 * CPR;
    for (int c = tid; c < NC * (DUAL ? 2 : 1); c += 256) {
      int cc = c;
      const unsigned short* src = A;
      unsigned short* dstp = sA;
      if (DUAL && cc >= NC) {
        cc -= NC;
        src = A2;
        dstp = sA + 16384;
      }
      int row = cc / CPR, slot = cc % CPR;
      int grow = r0 + row;
      uint4 u = {0u, 0u, 0u, 0u};
      if (grow < N) u = *(const uint4*)(src + (size_t)grow * K + slot * 8);
      int baddr = row * (K * 2) + ((slot * 16) ^ ((row & 7) << 4));
      *(uint4*)((char*)dstp + baddr) = u;
    }
  }
  __syncthreads();

  const int lane = tid & 63, wid = tid >> 6;
  const int wr = wid >> 1, wc = wid & 1;
  const int lr = lane & 15, lg = lane >> 4;

  f32x4 acc[4][4] = {};

#pragma unroll
  for (int ks = 0; ks < K / 32; ++ks) {
    short8 af[4], wf[4];
#pragma unroll
    for (int m = 0; m < 4; ++m) {
      int row = wr * 64 + m * 16 + lr;
      int kb = (ks * 32 + lg * 8) * 2;
      af[m] = *(const short8*)((const char*)sA + row * (K * 2) + (kb ^ ((row & 7) << 4)));
    }
#pragma unroll
    for (int n = 0; n < 4; ++n) {
      int h = wc * 64 + n * 16 + lr;
      wf[n] = *(const short8*)(W1 + (size_t)h * K + ks * 32 + lg * 8);
    }
#pragma unroll
    for (int m = 0; m < 4; ++m)
#pragma unroll
      for (int n = 0; n < 4; ++n)
        acc[m][n] = __builtin_amdgcn_mfma_f32_16x16x32_bf16(af[m], wf[n], acc[m][n], 0, 0, 0);
    if constexpr (DUAL) {
      short8 af2[4], wf2[4];
#pragma unroll
      for (int m = 0; m < 4; ++m) {
        int row = wr * 64 + m * 16 + lr;
        int kb = (ks * 32 + lg * 8) * 2;
        af2[m] = *(const short8*)((const char*)(sA + 16384) + row * (K * 2) +
                                  (kb ^ ((row & 7) << 4)));
      }
#pragma unroll
      for (int n = 0; n < 4; ++n) {
        int h = wc * 64 + n * 16 + lr;
        wf2[n] = *(const short8*)(W2 + (size_t)h * K + ks * 32 + lg * 8);
      }
#pragma unroll
      for (int m = 0; m < 4; ++m)
#pragma unroll
        for (int n = 0; n < 4; ++n)
          acc[m][n] = __builtin_amdgcn_mfma_f32_16x16x32_bf16(af2[m], wf2[n], acc[m][n], 0, 0, 0);
    }
  }
  __syncthreads();  // all waves done reading sA; reuse it for output repack

  // ---- epilogue: bias, BN partials, LDS repack -> coalesced bf16 store
  float bcol[4];
#pragma unroll
  for (int n = 0; n < 4; ++n) bcol[n] = bias[wc * 64 + n * 16 + lr];
  float sum[4] = {0.f, 0.f, 0.f, 0.f}, sq[4] = {0.f, 0.f, 0.f, 0.f};
#pragma unroll
  for (int m = 0; m < 4; ++m)
#pragma unroll
    for (int n = 0; n < 4; ++n) {
      int col = wc * 64 + n * 16 + lr;
#pragma unroll
      for (int r = 0; r < 4; ++r) {
        int row = wr * 64 + m * 16 + lg * 4 + r;
        float y = acc[m][n][r] + bcol[n];
        if constexpr (FUSE_BN) {
          if (r0 + row < N) {
            sum[n] += y;
            sq[n] = fmaf(y, y, sq[n]);
          }
        }
        int baddr = row * 256 + ((col * 2) ^ (((row >> 2) & 3) << 5));
        *(unsigned short*)((char*)sA + baddr) = f2bf(y);
      }
    }
  if constexpr (FUSE_BN) {
#pragma unroll
    for (int n = 0; n < 4; ++n) {
      sum[n] += __shfl_xor(sum[n], 16);
      sum[n] += __shfl_xor(sum[n], 32);
      sq[n] += __shfl_xor(sq[n], 16);
      sq[n] += __shfl_xor(sq[n], 32);
    }
    if (lg == 0) {
      float* st = stats + (size_t)(blockIdx.x & 31) * 256;
#pragma unroll
      for (int n = 0; n < 4; ++n) {
        int col = wc * 64 + n * 16 + lr;
        atomicAdd(&st[col], sum[n]);
        atomicAdd(&st[128 + col], sq[n]);
      }
    }
  }
  __syncthreads();
  for (int c = tid; c < 2048; c += 256) {
    int row = c >> 4, slot = c & 15;
    int grow = r0 + row;
    if (grow < N) {
      uint4 v = *(const uint4*)((const char*)sA + row * 256 +
                                ((slot * 16) ^ (((row >> 2) & 3) << 5)));
      *(uint4*)(outb + (size_t)grow * HD + slot * 8) = v;
    }
  }
}

// ---------------------------------------------------------------- batch norm tail
__global__ void bn_final_k(const float* __restrict__ stats, const float* __restrict__ g,
                           const float* __restrict__ b, float* __restrict__ ss, float invN) {
  int c = threadIdx.x;  // 128
  float s = 0.f, q = 0.f;
  for (int r = 0; r < 32; ++r) {
    s += stats[r * 256 + c];
    q += stats[r * 256 + 128 + c];
  }
  float m = s * invN;
  float v = fmaf(-m, m, q * invN);
  v = v < 0.f ? 0.f : v;
  float sc = g[c] * rsqrtf(v + 1e-5f);
  ss[c] = sc;
  ss[128 + c] = fmaf(-m, sc, b[c]);
}

__launch_bounds__(256)
__global__ void bn_apply_relu_bf(const unsigned short* __restrict__ y,
                                 const float* __restrict__ ss, unsigned short* __restrict__ xb,
                                 float* __restrict__ xf, int N) {
  int i = blockIdx.x * 256 + threadIdx.x;  // chunks of 8 bf16
  if (i >= N * 16) return;
  int row = i >> 4, cg = (i & 15) * 8;
  uint4 v = *(const uint4*)(y + (size_t)i * 8);
  float4 sc0 = *(const float4*)(ss + cg);
  float4 sc1 = *(const float4*)(ss + cg + 4);
  float4 sh0 = *(const float4*)(ss + 128 + cg);
  float4 sh1 = *(const float4*)(ss + 132 + cg);
  float o0 = fmaxf(fmaf(bf2f(v.x & 0xffffu), sc0.x, sh0.x), 0.f);
  float o1 = fmaxf(fmaf(bf2f(v.x >> 16), sc0.y, sh0.y), 0.f);
  float o2 = fmaxf(fmaf(bf2f(v.y & 0xffffu), sc0.z, sh0.z), 0.f);
  float o3 = fmaxf(fmaf(bf2f(v.y >> 16), sc0.w, sh0.w), 0.f);
  float o4 = fmaxf(fmaf(bf2f(v.z & 0xffffu), sc1.x, sh1.x), 0.f);
  float o5 = fmaxf(fmaf(bf2f(v.z >> 16), sc1.y, sh1.y), 0.f);
  float o6 = fmaxf(fmaf(bf2f(v.w & 0xffffu), sc1.z, sh1.z), 0.f);
  float o7 = fmaxf(fmaf(bf2f(v.w >> 16), sc1.w, sh1.w), 0.f);
  uint4 ob;
  ob.x = (unsigned)f2bf(o0) | ((unsigned)f2bf(o1) << 16);
  ob.y = (unsigned)f2bf(o2) | ((unsigned)f2bf(o3) << 16);
  ob.z = (unsigned)f2bf(o4) | ((unsigned)f2bf(o5) << 16);
  ob.w = (unsigned)f2bf(o6) | ((unsigned)f2bf(o7) << 16);
  *(uint4*)(xb + (size_t)i * 8) = ob;
  if (xf) {
    float4 a = {o0, o1, o2, o3};
    float4 bq = {o4, o5, o6, o7};
    *(float4*)(xf + (size_t)row * HD + cg) = a;
    *(float4*)(xf + (size_t)row * HD + cg + 4) = bq;
  }
}

// ---------------------------------------------------------------- launch
extern "C" void kernel_launch(void* const* d_in, const int* in_sizes, int n_in,
                              void* d_out, int out_size, void* d_ws, size_t ws_size,
                              hipStream_t stream) {
  const float* x_user = (const float*)d_in[0];
  const float* x_event = (const float*)d_in[1];
  const int* edge_user = (const int*)d_in[2];
  const int* edge_event = (const int*)d_in[3];
  const float* up_W = (const float*)d_in[4];
  const float* up_b = (const float*)d_in[5];
  const float* ep_W = (const float*)d_in[6];
  const float* ep_b = (const float*)d_in[7];
  const float* u_Wl = (const float*)d_in[8];
  const float* u_bl = (const float*)d_in[9];
  const float* u_Wr = (const float*)d_in[10];
  const float* u_bng = (const float*)d_in[11];
  const float* u_bnb = (const float*)d_in[12];
  const float* e_Wl = (const float*)d_in[13];
  const float* e_bl = (const float*)d_in[14];
  const float* e_Wr = (const float*)d_in[15];
  const float* e_bng = (const float*)d_in[16];
  const float* e_bnb = (const float*)d_in[17];
  (void)in_sizes; (void)n_in; (void)out_size; (void)ws_size;

  float* xu_out = (float*)d_out;                    // [NUSER][128] fp32
  float* xe_out = xu_out + (size_t)NUSER * HD;      // [NEVENT][128] fp32

  char* w = (char*)d_ws;
  unsigned short* xu_bf = (unsigned short*)w;  w += (size_t)NUSER * HD * 2;   // 51.2 MB
  unsigned short* xe_bf = (unsigned short*)w;  w += (size_t)NEVENT * HD * 2;  // 12.8 MB
  unsigned short* aggb  = (unsigned short*)w;  w += (size_t)NUSER * HD * 2;   // 51.2 MB (pull out + gemm out)
  unsigned short* wbf   = (unsigned short*)w;  w += (size_t)196608 * 2;       // 384 KB
  int* rp_u  = (int*)w;  w += ((size_t)NUSER + 64) * 4;
  int* cur_u = (int*)w;  w += (size_t)NUSER * 4;
  int* ei_u  = (int*)w;  w += (size_t)NEDGE * 4;
  int* rp_e  = (int*)w;  w += ((size_t)NEVENT + 64) * 4;
  int* cur_e = (int*)w;  w += (size_t)NEVENT * 4;
  int* ei_e  = (int*)w;  w += (size_t)NEDGE * 4;
  int* part  = (int*)w;  w += 4096 * 4;
  float* stats = (float*)w;  w += (size_t)4 * 32 * 256 * 4;  // 4 regions x 32 replicas x 256
  float* ss = (float*)w;     w += 256 * 4;

  const unsigned short* wb_up = wbf;
  const unsigned short* wb_ep = wbf + 32768;
  const unsigned short* wb_uWl = wbf + 65536;
  const unsigned short* wb_uWr = wbf + 98304;
  const unsigned short* wb_eWl = wbf + 131072;
  const unsigned short* wb_eWr = wbf + 163840;

  // ---- CSR build (both directions), reused by both layers
  hipMemsetAsync(cur_u, 0, (size_t)NUSER * 4, stream);
  hipMemsetAsync(cur_e, 0, (size_t)NEVENT * 4, stream);
  hipMemsetAsync(stats, 0, (size_t)4 * 32 * 256 * 4, stream);
  count_edges<<<2048, 256, 0, stream>>>(edge_user, cur_u, NEDGE);
  count_edges<<<2048, 256, 0, stream>>>(edge_event, cur_e, NEDGE);
  int nbu = (NUSER + 255) / 256;   // 782
  int nbe = (NEVENT + 255) / 256;  // 196
  scan_blocks<<<nbu, 256, 0, stream>>>(cur_u, rp_u, part, NUSER);
  scan_partials<<<1, 1024, 0, stream>>>(part, nbu);
  add_offsets<<<nbu, 256, 0, stream>>>(rp_u, cur_u, part, NUSER, NEDGE);
  scan_blocks<<<nbe, 256, 0, stream>>>(cur_e, rp_e, part, NEVENT);
  scan_partials<<<1, 1024, 0, stream>>>(part, nbe);
  add_offsets<<<nbe, 256, 0, stream>>>(rp_e, cur_e, part, NEVENT, NEDGE);
  fill_csr<<<2048, 256, 0, stream>>>(edge_user, edge_event, cur_u, ei_u, NEDGE);
  fill_csr<<<2048, 256, 0, stream>>>(edge_event, edge_user, cur_e, ei_e, NEDGE);

  // ---- weights -> bf16
  conv_weights<<<768, 256, 0, stream>>>(up_W, ep_W, u_Wl, u_Wr, e_Wl, e_Wr, wbf);

  // ---- initial projections (fp32 in, bf16 MFMA, bf16 out)
  int gbu = (NUSER + 127) / 128, gbe = (NEVENT + 127) / 128;
  gemm_mfma<FU, true, false, false><<<gbu, 256, 0, stream>>>(
      x_user, wb_up, nullptr, nullptr, up_b, xu_bf, nullptr, NUSER);
  gemm_mfma<FU, true, false, false><<<gbe, 256, 0, stream>>>(
      x_event, wb_ep, nullptr, nullptr, ep_b, xe_bf, nullptr, NEVENT);

  // ---- layers
  for (int l = 0; l < NLAYER; ++l) {
    float* stU = stats + (size_t)(l * 2 + 0) * 32 * 256;
    float* stE = stats + (size_t)(l * 2 + 1) * 32 * 256;
    // event -> user
    pull_mean_bf<<<NUSER / 4, 256, 0, stream>>>(xe_bf, rp_u, ei_u, aggb, NUSER);
    gemm_mfma<HD, false, true, true><<<gbu, 256, 0, stream>>>(
        aggb, wb_uWl + (size_t)l * HD * HD, xu_bf, wb_uWr + (size_t)l * HD * HD,
        u_bl + (size_t)l * HD, aggb, stU, NUSER);
    bn_final_k<<<1, 128, 0, stream>>>(stU, u_bng + (size_t)l * HD, u_bnb + (size_t)l * HD,
                                      ss, 1.0f / (float)NUSER);
    bn_apply_relu_bf<<<(NUSER * 16 + 255) / 256, 256, 0, stream>>>(
        aggb, ss, xu_bf, (l == NLAYER - 1) ? xu_out : nullptr, NUSER);
    // user -> event
    pull_mean_bf<<<NEVENT / 4, 256, 0, stream>>>(xu_bf, rp_e, ei_e, aggb, NEVENT);
    gemm_mfma<HD, false, true, true><<<gbe, 256, 0, stream>>>(
        aggb, wb_eWl + (size_t)l * HD * HD, xe_bf, wb_eWr + (size_t)l * HD * HD,
        e_bl + (size_t)l * HD, aggb, stE, NEVENT);
    bn_final_k<<<1, 128, 0, stream>>>(stE, e_bng + (size_t)l * HD, e_bnb + (size_t)l * HD,
                                      ss, 1.0f / (float)NEVENT);
    bn_apply_relu_bf<<<(NEVENT * 16 + 255) / 256, 256, 0, stream>>>(
        aggb, ss, xe_bf, (l == NLAYER - 1) ? xe_out : nullptr, NEVENT);
  }
}